// Round 1
// baseline (578.341 us; speedup 1.0000x reference)
//
#include <hip/hip_runtime.h>
#include <hip/hip_bf16.h>
#include <cstdint>

typedef __hip_bfloat16 bf16;
typedef __attribute__((ext_vector_type(8))) short bfrag;   // 8 bf16 (4 VGPRs)
typedef __attribute__((ext_vector_type(4))) float facc;    // 4 fp32 acc

#define B_    16384
#define D_    1024
#define DOUT_ 1024
#define R_    8
#define DH_   512
#define RH_   4096

#define BM 128
#define BN 128
#define BK 64

#define AS1(p) ((const __attribute__((address_space(1))) void*)(p))
#define AS3(p) ((__attribute__((address_space(3))) void*)(p))

static __device__ __forceinline__ uint32_t pack2bf(float a, float b) {
    unsigned short ua = __builtin_bit_cast(unsigned short, __float2bfloat16(a));
    unsigned short ub = __builtin_bit_cast(unsigned short, __float2bfloat16(b));
    return (uint32_t)ua | ((uint32_t)ub << 16);
}

// ---------------- fp32 -> bf16 conversion (vectorized) ----------------
__global__ void k_cvt(const float* __restrict__ in, bf16* __restrict__ out, long n)
{
    long i = ((long)blockIdx.x * blockDim.x + threadIdx.x) * 4;
    if (i >= n) return;
    float4 v = *reinterpret_cast<const float4*>(in + i);
    uint2 o;
    o.x = pack2bf(v.x, v.y);
    o.y = pack2bf(v.z, v.w);
    *reinterpret_cast<uint2*>(out + i) = o;
}

// ---- W2 (R,DOUT,DH) -> B4 (DOUT, R*DH) with B4[o][r*DH+h] = W2[r][o][h] ----
__global__ void k_cvt_w2(const float* __restrict__ W2, bf16* __restrict__ out)
{
    int b = blockIdx.x;            // 0 .. R_*DOUT_-1
    int r = b >> 10;               // DOUT_ = 1024
    int o = b & 1023;
    const float4* src = reinterpret_cast<const float4*>(W2 + ((long)r * DOUT_ + o) * DH_);
    bf16* dst = out + (long)o * RH_ + r * DH_;
    int t = threadIdx.x;           // 0..127, covers 512 floats
    float4 v = src[t];
    uint2 p;
    p.x = pack2bf(v.x, v.y);
    p.y = pack2bf(v.z, v.w);
    *reinterpret_cast<uint2*>(dst + t * 4) = p;
}

// ---------------- gate = softmax(x @ Wg.T + bg) ----------------
__global__ __launch_bounds__(256) void k_gate(const float* __restrict__ x,
                                              const float* __restrict__ Wg,
                                              const float* __restrict__ bg,
                                              float* __restrict__ gate)
{
    __shared__ float sWg[R_ * D_];
    __shared__ float sbg[R_];
    for (int i = threadIdx.x; i < R_ * D_ / 4; i += 256)
        reinterpret_cast<float4*>(sWg)[i] = reinterpret_cast<const float4*>(Wg)[i];
    if (threadIdx.x < R_) sbg[threadIdx.x] = bg[threadIdx.x];
    __syncthreads();

    const int lane = threadIdx.x & 63;
    const int wave = threadIdx.x >> 6;
    const int row  = blockIdx.x * 4 + wave;     // grid = B_/4

    const float4* xr = reinterpret_cast<const float4*>(x + (long)row * D_);
    float s[R_] = {};
    #pragma unroll
    for (int c = 0; c < 4; ++c) {
        float4 xv = xr[lane + c * 64];
        #pragma unroll
        for (int r = 0; r < R_; ++r) {
            float4 wv = reinterpret_cast<const float4*>(sWg + r * D_)[lane + c * 64];
            s[r] += xv.x * wv.x + xv.y * wv.y + xv.z * wv.z + xv.w * wv.w;
        }
    }
    #pragma unroll
    for (int r = 0; r < R_; ++r) {
        float v = s[r];
        #pragma unroll
        for (int off = 32; off > 0; off >>= 1) v += __shfl_xor(v, off);
        s[r] = v + sbg[r];
    }
    float m = s[0];
    #pragma unroll
    for (int r = 1; r < R_; ++r) m = fmaxf(m, s[r]);
    float den = 0.f;
    #pragma unroll
    for (int r = 0; r < R_; ++r) { s[r] = __expf(s[r] - m); den += s[r]; }
    float inv = 1.f / den;
    if (lane < R_) gate[(long)row * R_ + lane] = s[lane] * inv;
}

// ---------------- bf16 MFMA GEMM: C = A(MxK) @ B(NxK)^T + epilogue ----------------
// EPI 0: C(bf16) = dot + bias[col]
// EPI 1: C(bf16) = relu(dot + bias[col]) * gate[row][col>>9]
// EPI 2: C(f32)  = dot + sum_r gate[row][r]*b2[r][col]
template <int EPI>
__global__ __launch_bounds__(256)
void k_gemm(const bf16* __restrict__ A, const bf16* __restrict__ Bm,
            const float* __restrict__ bias, const float* __restrict__ gate,
            const float* __restrict__ b2v, void* __restrict__ Cout,
            int M, int N, int K, int gate_row0)
{
    __shared__ bf16 As[BM * BK];
    __shared__ bf16 Bs[BN * BK];

    const int tid  = threadIdx.x;
    const int lane = tid & 63;
    const int wave = tid >> 6;
    const int wr   = wave >> 1;
    const int wc   = wave & 1;
    const int bn0  = blockIdx.x * BN;
    const int bm0  = blockIdx.y * BM;

    const int lrow = lane & 15;
    const int kgrp = lane >> 4;

    const int srow = tid >> 3;        // 0..31
    const int scol = (tid & 7) * 8;   // 0,8,..,56

    facc acc[4][4];
    #pragma unroll
    for (int m = 0; m < 4; ++m)
        #pragma unroll
        for (int n = 0; n < 4; ++n)
            acc[m][n] = facc{0.f, 0.f, 0.f, 0.f};

    for (int k0 = 0; k0 < K; k0 += BK) {
        __syncthreads();
        #pragma unroll
        for (int c = 0; c < 4; ++c) {
            const int r = c * 32 + srow;
            __builtin_amdgcn_global_load_lds(
                AS1(A + (long)(bm0 + r) * K + (k0 + scol)),
                AS3(&As[r * BK + scol]), 16, 0, 0);
            __builtin_amdgcn_global_load_lds(
                AS1(Bm + (long)(bn0 + r) * K + (k0 + scol)),
                AS3(&Bs[r * BK + scol]), 16, 0, 0);
        }
        __syncthreads();

        #pragma unroll
        for (int kk = 0; kk < 2; ++kk) {
            bfrag af[4], bfv[4];
            #pragma unroll
            for (int m = 0; m < 4; ++m)
                af[m] = *reinterpret_cast<const bfrag*>(
                    &As[(wr * 64 + m * 16 + lrow) * BK + kk * 32 + kgrp * 8]);
            #pragma unroll
            for (int n = 0; n < 4; ++n)
                bfv[n] = *reinterpret_cast<const bfrag*>(
                    &Bs[(wc * 64 + n * 16 + lrow) * BK + kk * 32 + kgrp * 8]);
            #pragma unroll
            for (int m = 0; m < 4; ++m)
                #pragma unroll
                for (int n = 0; n < 4; ++n)
                    acc[m][n] = __builtin_amdgcn_mfma_f32_16x16x32_bf16(
                        af[m], bfv[n], acc[m][n], 0, 0, 0);
        }
    }

    if constexpr (EPI == 2) {
        float* Cf = reinterpret_cast<float*>(Cout);
        float b2c[4][8];
        #pragma unroll
        for (int n = 0; n < 4; ++n) {
            const int col = bn0 + wc * 64 + n * 16 + lrow;
            #pragma unroll
            for (int r = 0; r < R_; ++r) b2c[n][r] = b2v[r * N + col];
        }
        #pragma unroll
        for (int m = 0; m < 4; ++m) {
            #pragma unroll
            for (int j = 0; j < 4; ++j) {
                const int row = bm0 + wr * 64 + m * 16 + kgrp * 4 + j;
                const float* g = gate + (long)(gate_row0 + row) * R_;
                float gv[8];
                #pragma unroll
                for (int r = 0; r < R_; ++r) gv[r] = g[r];
                #pragma unroll
                for (int n = 0; n < 4; ++n) {
                    const int col = bn0 + wc * 64 + n * 16 + lrow;
                    float sv = acc[m][n][j];
                    #pragma unroll
                    for (int r = 0; r < R_; ++r) sv += gv[r] * b2c[n][r];
                    Cf[(long)row * N + col] = sv;
                }
            }
        }
    } else {
        bf16* Cb = reinterpret_cast<bf16*>(Cout);
        #pragma unroll
        for (int n = 0; n < 4; ++n) {
            const int col = bn0 + wc * 64 + n * 16 + lrow;
            const float bi = bias[col];
            #pragma unroll
            for (int m = 0; m < 4; ++m) {
                #pragma unroll
                for (int j = 0; j < 4; ++j) {
                    const int row = bm0 + wr * 64 + m * 16 + kgrp * 4 + j;
                    float v = acc[m][n][j] + bi;
                    if constexpr (EPI == 1)
                        v = fmaxf(v, 0.f) * gate[(long)(gate_row0 + row) * R_ + (col >> 9)];
                    Cb[(long)row * N + col] = __float2bfloat16(v);
                }
            }
        }
    }
}

extern "C" void kernel_launch(void* const* d_in, const int* in_sizes, int n_in,
                              void* d_out, int out_size, void* d_ws, size_t ws_size,
                              hipStream_t stream)
{
    const float* x   = (const float*)d_in[0];
    const float* ipw = (const float*)d_in[1];
    const float* ipb = (const float*)d_in[2];
    const float* opw = (const float*)d_in[3];
    const float* opb = (const float*)d_in[4];
    const float* W1  = (const float*)d_in[5];
    const float* b1  = (const float*)d_in[6];
    const float* W2  = (const float*)d_in[7];
    const float* b2  = (const float*)d_in[8];
    const float* Wg  = (const float*)d_in[9];
    const float* bg  = (const float*)d_in[10];
    float* out = (float*)d_out;

    char* ws = (char*)d_ws;
    size_t off = 0;
    auto alloc = [&](size_t bytes) -> void* {
        void* p = ws + off;
        off += (bytes + 255) & ~(size_t)255;
        return p;
    };

    bf16* xb   = (bf16*)alloc((size_t)B_ * D_ * 2);     // x in bf16; later reused? no — att reuses it
    bf16* vb   = (bf16*)alloc((size_t)B_ * D_ * 2);     // v
    bf16* Wvb  = (bf16*)alloc((size_t)D_ * D_ * 2);
    bf16* Wob  = (bf16*)alloc((size_t)D_ * D_ * 2);
    bf16* W1b  = (bf16*)alloc((size_t)RH_ * D_ * 2);
    bf16* W2b  = (bf16*)alloc((size_t)DOUT_ * RH_ * 2);
    float* gate = (float*)alloc((size_t)B_ * R_ * 4);

    // h' chunk buffer: largest M-chunk that fits the workspace
    int mc = B_;
    while (off + (size_t)mc * RH_ * 2 > ws_size && mc > 1024) mc >>= 1;
    bf16* hb = (bf16*)alloc((size_t)mc * RH_ * 2);
    bf16* ab = xb;   // attended reuses xb (xb is dead after G1; gate reads fp32 x)

    // ---- conversions ----
    k_cvt<<<(B_ * D_) / 1024, 256, 0, stream>>>(x, xb, (long)B_ * D_);
    k_cvt<<<(D_ * D_) / 1024, 256, 0, stream>>>(ipw + (size_t)2 * D_ * D_, Wvb, (long)D_ * D_);
    k_cvt<<<(D_ * D_) / 1024, 256, 0, stream>>>(opw, Wob, (long)D_ * D_);
    k_cvt<<<(RH_ * D_) / 1024, 256, 0, stream>>>(W1, W1b, (long)RH_ * D_);
    k_cvt_w2<<<R_ * DOUT_, 128, 0, stream>>>(W2, W2b);

    // ---- gate (reads fp32 x directly) ----
    k_gate<<<B_ / 4, 256, 0, stream>>>(x, Wg, bg, gate);

    // ---- G1: v = x @ Wv^T + bv ----
    k_gemm<0><<<dim3(D_ / BN, B_ / BM), 256, 0, stream>>>(
        xb, Wvb, ipb + 2 * D_, nullptr, nullptr, vb, B_, D_, D_, 0);

    // ---- G2: attended = v @ Wout^T + bout ----
    k_gemm<0><<<dim3(D_ / BN, B_ / BM), 256, 0, stream>>>(
        vb, Wob, opb, nullptr, nullptr, ab, B_, D_, D_, 0);

    // ---- G3 + G4, chunked over M ----
    for (int m0 = 0; m0 < B_; m0 += mc) {
        // h' = relu(att @ W1cat^T + b1) * gate[:, r]
        k_gemm<1><<<dim3(RH_ / BN, mc / BM), 256, 0, stream>>>(
            ab + (size_t)m0 * D_, W1b, b1, gate, nullptr, hb, mc, RH_, D_, m0);
        // out = h' @ W2cat + gate @ b2
        k_gemm<2><<<dim3(DOUT_ / BN, mc / BM), 256, 0, stream>>>(
            hb, W2b, nullptr, gate, b2, out + (size_t)m0 * DOUT_, mc, DOUT_, RH_, m0);
    }
}